// Round 2
// 242.159 us; speedup vs baseline: 1.0085x; 1.0085x over previous
//
#include <hip/hip_runtime.h>
#include <stdint.h>

typedef float  v4f __attribute__((ext_vector_type(4)));
typedef short  v4s __attribute__((ext_vector_type(4)));

#define LOG2E 1.44269504088896340736f
#define LN2   0.69314718055994530942f

static __device__ __forceinline__ float fexp2(float x){ return __builtin_amdgcn_exp2f(x); }
static __device__ __forceinline__ float flog2(float x){ return __builtin_amdgcn_logf(x); }

// pack two f32 -> two bf16 (round-half-up) in one dword via v_perm — PROVEN in R1-R4.
// (R5's __builtin_amdgcn_cvt_pk_bf16_f32 produced NaN output; suspected bad lowering.)
static __device__ __forceinline__ unsigned pkbf(float a, float b){
  unsigned ua = __float_as_uint(a) + 0x8000u;
  unsigned ub = __float_as_uint(b) + 0x8000u;
  return __builtin_amdgcn_perm(ub, ua, 0x07060302u);
}
static __device__ __forceinline__ v4s pack4(const v4f& m){
  union { unsigned u[2]; v4s s; } t;
  t.u[0] = pkbf(m.x, m.y);
  t.u[1] = pkbf(m.z, m.w);
  return t.s;
}

static __device__ __forceinline__ v4f mfma16(v4s a, v4s b, v4f c){
#if __has_builtin(__builtin_amdgcn_mfma_f32_16x16x16bf16_1k)
  return __builtin_amdgcn_mfma_f32_16x16x16bf16_1k(a, b, c, 0, 0, 0);
#else
  v4f r = c;
  asm("s_nop 1\n\tv_mfma_f32_16x16x16_bf16 %0, %1, %2, %0\n\ts_nop 7\n\ts_nop 1"
      : "+v"(r) : "v"(a), "v"(b));
  return r;
#endif
}

static __device__ __forceinline__ float sel4(const v4f& e4, int s){
  float a = (s & 1) ? e4.y : e4.x;
  float c = (s & 1) ? e4.w : e4.z;
  return (s & 2) ? c : a;
}

// ---------------- Phase 1 ----------------
// One chain per wave: 4 (batch,chunk) 8x8 transfer-matrix products via one
// 16x16x16 bf16 MFMA (blockdiag(E^T,E^T), 2x2 column-octets).
// Lane roles: n=lane&15, q=lane>>4, qr=q&1 (row half r0=4*qr), cn=n&7 (column),
// matrix mm=((q>>1)<<1)|(n>>3). Recurrence P' = diag(exp(em_t)) * E^T * P.
// D (C-layout) == next B (B-layout) -> zero-shuffle feedback.
// Pipelining: em/tags prefetched 2 blocks ahead (3 buffers); exps for block kb+1
// computed+written to the LDS broadcast slot during block kb (full-block distance
// between ds_write and its ds_reads). Per-wave DS ops are in-order: no barrier.
// R6: masks from one per-kb __ballot (tags monotone) instead of per-step g0/g1
// loads; wave-uniform dead-break.
// R7 FIX: R6's per-lane branch put MFMA under divergent EXEC -> NaN. Triage is
// now WAVE-UNIFORM (allAlive = bal all-ones); the masked body is branch-free
// cndmask per lane, so every MFMA executes with full EXEC.

template<bool MASKED>
__device__ __forceinline__ void chunk_loop(
    const float* __restrict__ emb, const int* __restrict__ tgb, int c,
    const float* s_trans, const float* s_end, float* s_slot,
    v4s afrag, int qr, int r0, int cn, bool lastChunk,
    v4f& master, v4s& bfrag, float& lZ, float& num)
{
  v4f eo[3]; int tc[3], tp[3];

  auto loadK = [&](int kb, int buf){
    const int t0 = kb << 3;
    eo[buf] = *(const v4f*)(emb + (size_t)(t0 + cn) * 8u);
    tc[buf] = tgb[t0 + cn];
    int ip = t0 + cn - 1;
    if (c == 0 && ip < 0) ip = 0;        // global t=0: value unused
    tp[buf] = tgb[ip];
  };

  auto expwrite = [&](const v4f& e, int par){
    v4f ed;
    ed.x = fexp2(e.x * LOG2E); ed.y = fexp2(e.y * LOG2E);
    ed.z = fexp2(e.z * LOG2E); ed.w = fexp2(e.w * LOG2E);
    *(v4f*)(s_slot + (par << 5) + (cn << 2)) = ed;   // ds_write_b128
  };

  loadK(0, 0); loadK(1, 1); loadK(2, 2);
  expwrite(eo[0], 0);

#pragma unroll
  for (int kb = 0; kb < 8; ++kb){
    const int buf = kb % 3;

    // distributed numerator for step t = kb*8 + cn (must precede dead-break:
    // the end_transitions add fires on the first masked step of the batch)
    const bool sk0 = (!MASKED) && (c == 0) && (kb == 0);
    {
      bool act = MASKED ? (tc[buf] != 0) : true;
      if (sk0 && cn == 0) act = false;
      const int s = tc[buf] - 1;
      const float ev = sel4(eo[buf], s);
      num += (act && ((s >> 2) == qr)) ? ev : 0.f;
      const float tv = s_trans[(((tp[buf] - 1) & 7) << 3) + (s & 7)];
      num += (act && (qr == 0)) ? tv : 0.f;
      if (MASKED && (tp[buf] != 0) && (tc[buf] == 0) && (qr == 0))
        num += s_end[tp[buf] - 1];
    }

    // per-kb mask byte from one ballot; tags are monotone -> all-zero kb
    // means every later step is masked too: stop the chunk. Both octets of a
    // matrix see identical bytes, so mb is coherent per matrix.
    unsigned mb = 0xffu;
    bool allAlive = true;                 // wave-uniform
    if (MASKED){
      const unsigned long long bal = __ballot(tc[buf] != 0);
      if (bal == 0ull) break;             // wave-uniform: all 4 matrices dead
      mb = (unsigned)(bal >> (threadIdx.x & 56)) & 0xffu;
      allAlive = (bal == ~0ull);
    }

    // broadcast exps for this block (written one block ago)
    v4f e8[8];
    const float* sl = s_slot + ((kb & 1) << 5);
#pragma unroll
    for (int j = 0; j < 8; ++j) e8[j] = *(const v4f*)(sl + (j << 2));

    // exps for next block -> other parity slot (distance = one full block)
    if (kb + 1 < 8) expwrite(eo[(kb + 1) % 3], (kb + 1) & 1);
    if (kb + 3 < 8) loadK(kb + 3, buf);

    // 8 recurrence steps — branch is wave-uniform; MFMA always full-EXEC
    if (!MASKED || allAlive){
#pragma unroll
      for (int j = 0; j < 8; ++j){
        if (sk0 && j == 0) continue;     // global t=0 handled in phase 2
        v4f zero = {0.f, 0.f, 0.f, 0.f};
        v4f d = mfma16(afrag, bfrag, zero);
        const v4f e = e8[j];
        master.x = d.x * e.x; master.y = d.y * e.y;
        master.z = d.z * e.z; master.w = d.w * e.w;
        bfrag = pack4(master);
      }
    } else {
#pragma unroll
      for (int j = 0; j < 8; ++j){
        v4f zero = {0.f, 0.f, 0.f, 0.f};
        v4f d = mfma16(afrag, bfrag, zero);
        const v4f e = e8[j];
        const bool v = (mb >> j) & 1u;   // per-lane cndmask, no branch
        master.x = v ? d.x * e.x : master.x;
        master.y = v ? d.y * e.y : master.y;
        master.z = v ? d.z * e.z : master.z;
        master.w = v ? d.w * e.w : master.w;
        bfrag = pack4(master);
      }
    }

    if (kb & 1){                          // renorm every 16 steps
      float mx = fmaxf(fmaxf(master.x, master.y), fmaxf(master.z, master.w));
      mx = fmaxf(mx, __shfl_xor(mx, 16, 64));
      const float inv = __builtin_amdgcn_rcpf(mx);
      master.x *= inv; master.y *= inv; master.z *= inv; master.w *= inv;
      lZ += flog2(mx);
      bfrag = pack4(master);
    }
  }

  if (MASKED && lastChunk){
    const int lt = tgb[63];               // tag at global t = L-1
    if ((lt != 0) && (qr == 0) && (cn == 0)) num += s_end[lt - 1];
  }
}

__global__ __launch_bounds__(256, 4)
void crf_phase1(const float* __restrict__ em,
                const float* __restrict__ trans,
                const float* __restrict__ endt,
                const int*   __restrict__ tags,
                float* __restrict__ ws)
{
  const int tid  = threadIdx.x;
  const int lane = tid & 63;
  const int n = lane & 15, q = lane >> 4, qr = q & 1, r0 = qr << 2, cn = n & 7;
  const int mm = ((q >> 1) << 1) | (n >> 3);
  const int p  = (blockIdx.x << 4) + ((tid >> 6) << 2) + mm;
  const int c  = p >> 11;                 // chunk id (S=64, C=32)
  const int bm = p & 2047;                // batch id

  __shared__ float s_trans[64];
  __shared__ float s_end[8];
  __shared__ float s_e[32 * 68];          // 32 groups x (2 slots x 32 + 4 pad)
  if (tid < 64) s_trans[tid] = trans[tid];
  if (tid < 8)  s_end[tid]  = endt[tid];
  __syncthreads();

  // constant A fragment: blockdiag(E^T, E^T); A[m][k], m=n, k=4q+j
  v4s afrag;
  {
    float av[4];
#pragma unroll
    for (int j = 0; j < 4; ++j){
      const int k = (q << 2) + j;
      float v = 0.f;
      if (n < 8 && k < 8)        v = fexp2(s_trans[k * 8 + n] * LOG2E);
      else if (n >= 8 && k >= 8) v = fexp2(s_trans[(k - 8) * 8 + (n - 8)] * LOG2E);
      av[j] = v;
    }
    union { unsigned u[2]; v4s s; } t;
    t.u[0] = pkbf(av[0], av[1]);
    t.u[1] = pkbf(av[2], av[3]);
    afrag = t.s;
  }

  const float* emb = em   + ((size_t)bm * 2048u + (size_t)c * 64u) * 8u + (unsigned)r0;
  const int*   tgb = tags + (size_t)bm * 2048u + (size_t)c * 64u;
  float* s_slot = &s_e[(tid >> 3) * 68];

  // P = identity
  v4f master;
  master.x = (r0 + 0 == cn) ? 1.f : 0.f;
  master.y = (r0 + 1 == cn) ? 1.f : 0.f;
  master.z = (r0 + 2 == cn) ? 1.f : 0.f;
  master.w = (r0 + 3 == cn) ? 1.f : 0.f;
  v4s bfrag = pack4(master);
  float num = 0.f, lZ = 0.f;

  if (c <= 15){                            // steps < 1024: never masked
    chunk_loop<false>(emb, tgb, c, s_trans, s_end, s_slot,
                      afrag, qr, r0, cn, false, master, bfrag, lZ, num);
  } else {
    const bool fz = (tgb[0] == 0);
    if (__ballot(fz) == ~0ull){            // all 4 pairs fully masked: identity
      const int pv = tgb[-1];
      if ((pv != 0) && (qr == 0) && (cn == 0)) num = s_end[pv - 1];
    } else {
      chunk_loop<true>(emb, tgb, c, s_trans, s_end, s_slot,
                       afrag, qr, r0, cn, (c == 31), master, bfrag, lZ, num);
    }
  }

  // ---- store, [c][entry-pair][b] layout (phase-2 coalescing) ----
  float2* ws2 = ((float2*)ws) + (size_t)c * 40u * 2048u + (unsigned)bm;
  const int e0 = (cn << 3) + r0;           // entry e = col*8 + row (even)
  float2 v01; v01.x = master.x; v01.y = master.y;
  float2 v23; v23.x = master.z; v23.y = master.w;
  ws2[(size_t)(e0 >> 1) * 2048u]       = v01;
  ws2[(size_t)((e0 >> 1) + 1) * 2048u] = v23;
  if (qr == 0)
    ((float*)(ws2 + (size_t)((64 + cn) >> 1) * 2048u))[cn & 1] = lZ;
  num += __shfl_xor(num, 1, 64);
  num += __shfl_xor(num, 2, 64);
  num += __shfl_xor(num, 4, 64);
  num += __shfl_xor(num, 16, 64);
  if (qr == 0 && cn == 0)
    ((float*)(ws2 + (size_t)36 * 2048u))[0] = num;
}

// ---------------- Phase 2: per-batch combine of chunk matrices ----------------
// 8 lanes per batch (lane j holds alpha[row j]); 16384 threads = 256 waves.
// R6: launched as 256 one-wave blocks (was 64x256) so the 256 waves spread
// over all 256 CUs instead of 64 — the scan is a latency-bound serial chain
// of dependent shuffles, so CU coverage is the whole game.
// Per chunk: ~10 scalar loads/lane, 3-chunk-deep rotating prefetch (<=30
// outstanding loads, under the vmcnt limit that broke the R3 version).
__global__ __launch_bounds__(64)
void crf_phase2(const float* __restrict__ em,
                const float* __restrict__ strt,
                const float* __restrict__ endt,
                const int*   __restrict__ tags,
                const float* __restrict__ ws,
                float* __restrict__ out)
{
  const int tid  = threadIdx.x;
  const int lane = tid & 63;
  const int gt = (blockIdx.x << 6) + tid;
  const int b = gt >> 3;                   // batch
  const int j = gt & 7;                    // alpha row
  const int gbase = lane & 56;             // first lane of this batch's group

  // per-lane float offsets into ws
  const unsigned poff = ((unsigned)(j >> 1) << 12) + (unsigned)(j & 1) + ((unsigned)b << 1);
  const float* wsf = ws;

  // alpha0 and numerator t=0 term
  const float al = strt[j] + em[(size_t)b * 16384u + (unsigned)j];
  const int s0 = tags[(size_t)b * 2048u] - 1;       // t=0 always valid
  float num = __shfl(al, gbase + s0, 64);           // strt[s0] + em0[s0]

  float mx = al;
  mx = fmaxf(mx, __shfl_xor(mx, 1, 64));
  mx = fmaxf(mx, __shfl_xor(mx, 2, 64));
  mx = fmaxf(mx, __shfl_xor(mx, 4, 64));
  float a = fexp2((al - mx) * LOG2E);
  float lZ2 = mx * LOG2E;

  float Pb[4][8], lsb[4], nmb[4];
  auto loadChunk = [&](int c, int s){
    const float* base = wsf + (size_t)c * 163840u;
#pragma unroll
    for (int i = 0; i < 8; ++i) Pb[s][i] = base[poff + (unsigned)i * 16384u];
    lsb[s] = base[131072u + poff];
    nmb[s] = base[147456u + ((unsigned)b << 1)];
  };

  loadChunk(0, 0); loadChunk(1, 1); loadChunk(2, 2);

#pragma unroll 4
  for (int c = 0; c < 32; ++c){
    const int s = c & 3;
    if (c + 3 < 32) loadChunk(c + 3, (c + 3) & 3);

    // group max of column scales
    float ls = lsb[s];
    float lm = ls;
    lm = fmaxf(lm, __shfl_xor(lm, 1, 64));
    lm = fmaxf(lm, __shfl_xor(lm, 2, 64));
    lm = fmaxf(lm, __shfl_xor(lm, 4, 64));
    const float w = a * fexp2(ls - lm);

    // alpha'[j] = sum_i w_i * P[col i][row j]
    float acc = 0.f;
#pragma unroll
    for (int i = 0; i < 8; ++i)
      acc += __shfl(w, gbase + i, 64) * Pb[s][i];

    float m2 = acc;
    m2 = fmaxf(m2, __shfl_xor(m2, 1, 64));
    m2 = fmaxf(m2, __shfl_xor(m2, 2, 64));
    m2 = fmaxf(m2, __shfl_xor(m2, 4, 64));
    a = acc * __builtin_amdgcn_rcpf(m2);
    lZ2 += lm + flog2(m2);
    num += nmb[s];
  }

  // denominator
  float t = a * fexp2(endt[j] * LOG2E);
  t += __shfl_xor(t, 1, 64);
  t += __shfl_xor(t, 2, 64);
  t += __shfl_xor(t, 4, 64);
  const float denom = (flog2(t) + lZ2) * LN2;

  float contrib = (j == 0) ? (denom - num) * (1.0f / 2048.0f) : 0.f;
  contrib += __shfl_xor(contrib, 8, 64);
  contrib += __shfl_xor(contrib, 16, 64);
  contrib += __shfl_xor(contrib, 32, 64);
  if (lane == 0) atomicAdd(out, contrib);
}

extern "C" void kernel_launch(void* const* d_in, const int* in_sizes, int n_in,
                              void* d_out, int out_size, void* d_ws, size_t ws_size,
                              hipStream_t stream) {
  const float* em    = (const float*)d_in[0];
  const float* trans = (const float*)d_in[1];
  const float* strt  = (const float*)d_in[2];
  const float* endt  = (const float*)d_in[3];
  const int*   tags  = (const int*)d_in[4];
  float* out = (float*)d_out;

  hipMemsetAsync(out, 0, sizeof(float), stream);
  // C=32 chunks of S=64 steps; 65536 (b,c) pairs, 4 per wave -> 4096 blocks of 256
  crf_phase1<<<4096, 256, 0, stream>>>(em, trans, endt, tags, (float*)d_ws);
  // 256 one-wave blocks: spread the 256 scan-waves across all 256 CUs
  crf_phase2<<<256, 64, 0, stream>>>(em, strt, endt, tags, (const float*)d_ws, out);
}